// Round 2
// baseline (1022.345 us; speedup 1.0000x reference)
//
#include <hip/hip_runtime.h>
#include <cstddef>
#include <cstdint>

typedef __bf16 bf16;
typedef __bf16 bf16x8 __attribute__((ext_vector_type(8)));
typedef __bf16 bf16x4 __attribute__((ext_vector_type(4)));
typedef float  f32x4  __attribute__((ext_vector_type(4)));

#define NTOK 49
#define QK_SCALE 0.17677669529663687f  // 32^-0.5

// workspace byte offsets
#define WS_WT   0          // 768*256 bf16 = 393216 B
#define WS_PJT  393216     // 256*256 bf16 = 131072 B
#define WS_P    524288     // 169*8 f32    = 5408 B (padded to 8192)
#define WS_RPBT 532480     // 8*64*64 f32  = 131072 B (end: 663552)

// ---------------- prep: transpose + bf16-convert weights ----------------
__global__ void prep_weights(const float* __restrict__ qkv_w, const float* __restrict__ proj_w,
                             bf16* __restrict__ wT, bf16* __restrict__ pjT) {
  int tid = blockIdx.x * 256 + threadIdx.x;
  if (tid < 768 * 256) {
    int n = tid >> 8, k = tid & 255;
    wT[tid] = (bf16)qkv_w[k * 768 + n];        // wT[n][k]
  } else {
    int t = tid - 768 * 256;
    int n = t >> 8, k = t & 255;
    pjT[t] = (bf16)proj_w[k * 256 + n];        // pjT[n][k]
  }
}

// ---------------- prep: position-bias MLP (169 rows, tiny) ----------------
__device__ __forceinline__ void mlp_layer(float* p, const float* g, const float* be,
                                          const float* w, const float* bb, int nout) {
  float m = 0.f;
#pragma unroll
  for (int j = 0; j < 16; ++j) m += p[j];
  m *= (1.f / 16.f);
  float v = 0.f;
#pragma unroll
  for (int j = 0; j < 16; ++j) { float d = p[j] - m; v += d * d; }
  v *= (1.f / 16.f);
  float rs = rsqrtf(v + 1e-5f);
  float t[16];
#pragma unroll
  for (int j = 0; j < 16; ++j) {
    float u = (p[j] - m) * rs * g[j] + be[j];
    t[j] = u > 0.f ? u : 0.f;
  }
  float o[16];
  for (int j = 0; j < nout; ++j) {
    float s = bb[j];
#pragma unroll
    for (int k = 0; k < 16; ++k) s += t[k] * w[k * nout + j];
    o[j] = s;
  }
  for (int j = 0; j < nout; ++j) p[j] = o[j];
}

__global__ void pos_mlp(const float* __restrict__ biases, const float* __restrict__ ppw,
                        const float* __restrict__ ppb,
                        const float* g1, const float* be1, const float* w1, const float* bb1,
                        const float* g2, const float* be2, const float* w2, const float* bb2,
                        const float* g3, const float* be3, const float* w3, const float* bb3,
                        float* __restrict__ p_out) {
  int i = blockIdx.x * blockDim.x + threadIdx.x;
  if (i >= 169) return;
  float p[16];
  float y0 = biases[2 * i], y1 = biases[2 * i + 1];
#pragma unroll
  for (int j = 0; j < 16; ++j) p[j] = y0 * ppw[j] + y1 * ppw[16 + j] + ppb[j];
  mlp_layer(p, g1, be1, w1, bb1, 16);
  mlp_layer(p, g2, be2, w2, bb2, 16);
  mlp_layer(p, g3, be3, w3, bb3, 8);
#pragma unroll
  for (int j = 0; j < 8; ++j) p_out[i * 8 + j] = p[j];
}

// rpbT[h][kt][qt], 8 x 64 x 64, with key-mask (-1e30 for kt>=49) baked in.
__global__ void build_rpbT(const float* __restrict__ p, const int* __restrict__ rel_idx,
                           float* __restrict__ rpbT) {
  int tid = blockIdx.x * 256 + threadIdx.x;
  if (tid >= 8 * 64 * 64) return;
  int h = tid >> 12, rem = tid & 4095, kt = rem >> 6, qt = rem & 63;
  float v;
  if (kt >= NTOK) v = -1e30f;                      // padded key -> masked
  else if (qt >= NTOK) v = 0.f;                    // padded query row -> harmless
  else v = p[rel_idx[qt * NTOK + kt] * 8 + h];
  rpbT[tid] = v;
}

// ---------------- fused per-window attention ----------------
// block = 256 threads (4 waves) = 1 window. Heads processed sequentially,
// wave w owns q-rows [16w, 16w+16) of every head. Shared (block-wide) LDS:
//   x_lds 64x264 bf16 (33792 B, reused as attn-out tile for proj)
//   sbuf  7424 bf16 (14848 B): q 64x40 | k 64x40 | vT 32x72 ; P 64x72 overlays q+k
// Total 48640 B -> 3 blocks/CU. Attention outputs held packed bf16 in regs.
// MFMA 16x16x32 bf16 layouts (m89/m92-verified):
//   A-frag: row = lane&15, k = 8*(lane>>4)+j ; B-frag: col = lane&15, k contiguous
//   C/D:    col = lane&15, row = 4*(lane>>4)+reg
__launch_bounds__(256, 3)
__global__ void attn_fused(const float* __restrict__ x, const bf16* __restrict__ wT,
                           const float* __restrict__ qkv_b, const bf16* __restrict__ pjT,
                           const float* __restrict__ proj_b, const float* __restrict__ rpbT,
                           float* __restrict__ out) {
  __shared__ __align__(16) bf16 x_lds[64 * 264];
  __shared__ __align__(16) bf16 sbuf[7424];

  const int b = blockIdx.x;
  const int tid = threadIdx.x;
  const int w = tid >> 6;
  const int lane = tid & 63;
  const int lg = lane >> 4;
  const int lr = lane & 15;
  const int rowbase = w * 16;          // this wave's q-row block
  const int myrow = rowbase + 4 * lg;  // + r2 = actual row for C-layout regs

  // ---- phase 0: x -> bf16 LDS, rows >= 49 zeroed ----
  const float* xb = x + (size_t)b * (NTOK * 256);
#pragma unroll
  for (int it = 0; it < 16; ++it) {
    int linear = (it * 256 + tid) * 4;
    int r = linear >> 8, c = linear & 255;
    float4 v = make_float4(0.f, 0.f, 0.f, 0.f);
    if (r < NTOK) v = *(const float4*)(xb + r * 256 + c);
    bf16x4 pk;
    pk[0] = (bf16)v.x; pk[1] = (bf16)v.y; pk[2] = (bf16)v.z; pk[3] = (bf16)v.w;
    *(bf16x4*)&x_lds[r * 264 + c] = pk;
  }
  __syncthreads();

  bf16* const q_lds = sbuf;            // 64 x 40
  bf16* const k_lds = sbuf + 2560;     // 64 x 40
  bf16* const vT    = sbuf + 5120;     // 32 x 72  (vT[d][token])
  bf16* const P     = sbuf;            // 64 x 72  overlays q+k after QK frag loads

  const f32x4 zero4 = {0.f, 0.f, 0.f, 0.f};
  bf16x4 o_pk[8][2];                   // per-head attn out, packed bf16 (32 VGPR)

  for (int h = 0; h < 8; ++h) {
    // ---- GEMM1: rows [16w,16w+16) x qkv cols of head h (q:0-1 k:2-3 v:4-5) ----
    f32x4 acc[6];
#pragma unroll
    for (int n = 0; n < 6; ++n) acc[n] = zero4;

#pragma unroll
    for (int kk = 0; kk < 8; ++kk) {
      bf16x8 afr = *(const bf16x8*)&x_lds[(rowbase + lr) * 264 + kk * 32 + 8 * lg];
#pragma unroll
      for (int n = 0; n < 6; ++n) {
        const int colb = (n < 2) ? (h * 32 + n * 16)
                       : (n < 4) ? (256 + h * 32 + (n - 2) * 16)
                                 : (512 + h * 32 + (n - 4) * 16);
        bf16x8 bfr = *(const bf16x8*)&wT[(size_t)(colb + lr) * 256 + kk * 32 + 8 * lg];
        acc[n] = __builtin_amdgcn_mfma_f32_16x16x32_bf16(afr, bfr, acc[n], 0, 0, 0);
      }
    }

    __syncthreads();  // (1) prev head's P/vT reads finished everywhere

    // ---- epilogue: stash q (pre-scaled), k, vT ----
#pragma unroll
    for (int n = 0; n < 2; ++n) {
      const float bias = qkv_b[h * 32 + n * 16 + lr];
#pragma unroll
      for (int r2 = 0; r2 < 4; ++r2)
        q_lds[(myrow + r2) * 40 + n * 16 + lr] = (bf16)((acc[n][r2] + bias) * QK_SCALE);
    }
#pragma unroll
    for (int n = 2; n < 4; ++n) {
      const float bias = qkv_b[256 + h * 32 + (n - 2) * 16 + lr];
#pragma unroll
      for (int r2 = 0; r2 < 4; ++r2)
        k_lds[(myrow + r2) * 40 + (n - 2) * 16 + lr] = (bf16)(acc[n][r2] + bias);
    }
#pragma unroll
    for (int n = 4; n < 6; ++n) {
      const float bias = qkv_b[512 + h * 32 + (n - 4) * 16 + lr];
      bf16x4 pk;
#pragma unroll
      for (int r2 = 0; r2 < 4; ++r2) pk[r2] = (bf16)(acc[n][r2] + bias);
      *(bf16x4*)&vT[((n - 4) * 16 + lr) * 72 + myrow] = pk;
    }
    __syncthreads();  // (2) q/k/vT visible

    // ---- QK^T: S rows [16w,16w+16) x all 64 key cols ----
    bf16x8 aq = *(const bf16x8*)&q_lds[(rowbase + lr) * 40 + 8 * lg];
    f32x4 s[4];
#pragma unroll
    for (int n = 0; n < 4; ++n) {
      bf16x8 bk = *(const bf16x8*)&k_lds[(n * 16 + lr) * 40 + 8 * lg];
      s[n] = __builtin_amdgcn_mfma_f32_16x16x32_bf16(aq, bk, zero4, 0, 0, 0);
    }

    // ---- add rel-pos bias (mask baked into rpbT) ----
    const float* rpbh = rpbT + h * 4096;
#pragma unroll
    for (int n = 0; n < 4; ++n) {
      f32x4 rv = *(const f32x4*)&rpbh[(n * 16 + lr) * 64 + myrow];
#pragma unroll
      for (int r2 = 0; r2 < 4; ++r2) s[n][r2] += rv[r2];
    }

    // ---- softmax over 64 cols: 4-reg fmax + 16-lane shfl reduce ----
    float inv_[4];
#pragma unroll
    for (int r2 = 0; r2 < 4; ++r2) {
      float mx = fmaxf(fmaxf(s[0][r2], s[1][r2]), fmaxf(s[2][r2], s[3][r2]));
#pragma unroll
      for (int off = 1; off <= 8; off <<= 1) mx = fmaxf(mx, __shfl_xor(mx, off, 64));
      float sum = 0.f;
#pragma unroll
      for (int n = 0; n < 4; ++n) {
        float e = __expf(s[n][r2] - mx);
        s[n][r2] = e;
        sum += e;
      }
#pragma unroll
      for (int off = 1; off <= 8; off <<= 1) sum += __shfl_xor(sum, off, 64);
      inv_[r2] = 1.f / sum;
    }

    __syncthreads();  // (3) all waves' q/k frag loads done; safe to overwrite with P

    // ---- P -> LDS (own rows only; PV reads them same-wave) ----
#pragma unroll
    for (int n = 0; n < 4; ++n)
#pragma unroll
      for (int r2 = 0; r2 < 4; ++r2)
        P[(myrow + r2) * 72 + n * 16 + lr] = (bf16)s[n][r2];

    // ---- PV: o(16x32) = P(16x64) @ v(64x32) ----
    f32x4 o[2];
    o[0] = zero4; o[1] = zero4;
#pragma unroll
    for (int ks = 0; ks < 2; ++ks) {
      bf16x8 ap = *(const bf16x8*)&P[(rowbase + lr) * 72 + ks * 32 + 8 * lg];
#pragma unroll
      for (int n2 = 0; n2 < 2; ++n2) {
        bf16x8 bv = *(const bf16x8*)&vT[(n2 * 16 + lr) * 72 + ks * 32 + 8 * lg];
        o[n2] = __builtin_amdgcn_mfma_f32_16x16x32_bf16(ap, bv, o[n2], 0, 0, 0);
      }
    }
#pragma unroll
    for (int n2 = 0; n2 < 2; ++n2)
#pragma unroll
      for (int r2 = 0; r2 < 4; ++r2)
        o_pk[h][n2][r2] = (bf16)(o[n2][r2] * inv_[r2]);
  }

  __syncthreads();  // all PV reads + all x_lds reads done

  // ---- assemble attn-out tile into x_lds region ----
#pragma unroll
  for (int h = 0; h < 8; ++h)
#pragma unroll
    for (int n2 = 0; n2 < 2; ++n2)
#pragma unroll
      for (int r2 = 0; r2 < 4; ++r2)
        x_lds[(myrow + r2) * 264 + h * 32 + n2 * 16 + lr] = o_pk[h][n2][r2];
  __syncthreads();

  // ---- proj: out = ao(64x256) @ proj_w + b; wave w owns 64 output cols ----
  f32x4 c2[4][4];
#pragma unroll
  for (int m = 0; m < 4; ++m)
#pragma unroll
    for (int n = 0; n < 4; ++n) c2[m][n] = zero4;
#pragma unroll 2
  for (int kk = 0; kk < 8; ++kk) {
    bf16x8 afr[4];
#pragma unroll
    for (int m = 0; m < 4; ++m)
      afr[m] = *(const bf16x8*)&x_lds[(m * 16 + lr) * 264 + kk * 32 + 8 * lg];
#pragma unroll
    for (int n = 0; n < 4; ++n) {
      bf16x8 bfr = *(const bf16x8*)&pjT[(size_t)(w * 64 + n * 16 + lr) * 256 + kk * 32 + 8 * lg];
#pragma unroll
      for (int m = 0; m < 4; ++m)
        c2[m][n] = __builtin_amdgcn_mfma_f32_16x16x32_bf16(afr[m], bfr, c2[m][n], 0, 0, 0);
    }
  }
  float* ob = out + (size_t)b * (NTOK * 256);
#pragma unroll
  for (int n = 0; n < 4; ++n) {
    const int col = w * 64 + n * 16 + lr;
    const float pb = proj_b[col];
#pragma unroll
    for (int m = 0; m < 4; ++m)
#pragma unroll
      for (int r2 = 0; r2 < 4; ++r2) {
        const int row = m * 16 + lg * 4 + r2;
        if (row < NTOK) ob[row * 256 + col] = c2[m][n][r2] + pb;
      }
  }
}

// ---------------- launcher ----------------
extern "C" void kernel_launch(void* const* d_in, const int* in_sizes, int n_in,
                              void* d_out, int out_size, void* d_ws, size_t ws_size,
                              hipStream_t stream) {
  (void)in_sizes; (void)n_in; (void)out_size; (void)ws_size;
  const float* x      = (const float*)d_in[0];
  const float* qkv_w  = (const float*)d_in[1];
  const float* qkv_b  = (const float*)d_in[2];
  const float* proj_w = (const float*)d_in[3];
  const float* proj_b = (const float*)d_in[4];
  const float* ppw    = (const float*)d_in[5];
  const float* ppb    = (const float*)d_in[6];
  const float* ln1_g  = (const float*)d_in[7];
  const float* ln1_b  = (const float*)d_in[8];
  const float* w1     = (const float*)d_in[9];
  const float* b1     = (const float*)d_in[10];
  const float* ln2_g  = (const float*)d_in[11];
  const float* ln2_b  = (const float*)d_in[12];
  const float* w2     = (const float*)d_in[13];
  const float* b2     = (const float*)d_in[14];
  const float* ln3_g  = (const float*)d_in[15];
  const float* ln3_b  = (const float*)d_in[16];
  const float* w3     = (const float*)d_in[17];
  const float* b3     = (const float*)d_in[18];
  const float* biases = (const float*)d_in[19];
  const int*   relidx = (const int*)d_in[20];

  char* ws = (char*)d_ws;
  bf16*  wT   = (bf16*)(ws + WS_WT);
  bf16*  pjT  = (bf16*)(ws + WS_PJT);
  float* p_ws = (float*)(ws + WS_P);
  float* rpbT = (float*)(ws + WS_RPBT);

  prep_weights<<<1024, 256, 0, stream>>>(qkv_w, proj_w, wT, pjT);
  pos_mlp<<<1, 256, 0, stream>>>(biases, ppw, ppb,
                                 ln1_g, ln1_b, w1, b1,
                                 ln2_g, ln2_b, w2, b2,
                                 ln3_g, ln3_b, w3, b3, p_ws);
  build_rpbT<<<128, 256, 0, stream>>>(p_ws, relidx, rpbT);
  attn_fused<<<4096, 256, 0, stream>>>(x, wT, qkv_b, pjT, proj_b, rpbT, (float*)d_out);
}

// Round 3
// 902.782 us; speedup vs baseline: 1.1324x; 1.1324x over previous
//
#include <hip/hip_runtime.h>
#include <cstddef>
#include <cstdint>

typedef __bf16 bf16;
typedef __bf16 bf16x8 __attribute__((ext_vector_type(8)));
typedef __bf16 bf16x4 __attribute__((ext_vector_type(4)));
typedef float  f32x4  __attribute__((ext_vector_type(4)));

#define NTOK 49
#define QK_SCALE 0.17677669529663687f   // 32^-0.5
#define LOG2E    1.4426950408889634f
#define QS       (QK_SCALE * LOG2E)     // folded into q at stash; softmax uses exp2

// workspace byte offsets
#define WS_WT   0          // 768*256 bf16 = 393216 B
#define WS_PJT  393216     // 256*256 bf16 = 131072 B
#define WS_P    524288     // 169*8 f32    = 5408 B (padded to 8192)
#define WS_RPBT 532480     // 8*64*64 f32  = 131072 B (end: 663552)

// ---------------- prep: transpose + bf16-convert weights ----------------
__global__ void prep_weights(const float* __restrict__ qkv_w, const float* __restrict__ proj_w,
                             bf16* __restrict__ wT, bf16* __restrict__ pjT) {
  int tid = blockIdx.x * 256 + threadIdx.x;
  if (tid < 768 * 256) {
    int n = tid >> 8, k = tid & 255;
    wT[tid] = (bf16)qkv_w[k * 768 + n];        // wT[n][k]
  } else {
    int t = tid - 768 * 256;
    int n = t >> 8, k = t & 255;
    pjT[t] = (bf16)proj_w[k * 256 + n];        // pjT[n][k]
  }
}

// ---------------- prep: position-bias MLP (169 rows, tiny) ----------------
__device__ __forceinline__ void mlp_layer(float* p, const float* g, const float* be,
                                          const float* w, const float* bb, int nout) {
  float m = 0.f;
#pragma unroll
  for (int j = 0; j < 16; ++j) m += p[j];
  m *= (1.f / 16.f);
  float v = 0.f;
#pragma unroll
  for (int j = 0; j < 16; ++j) { float d = p[j] - m; v += d * d; }
  v *= (1.f / 16.f);
  float rs = rsqrtf(v + 1e-5f);
  float t[16];
#pragma unroll
  for (int j = 0; j < 16; ++j) {
    float u = (p[j] - m) * rs * g[j] + be[j];
    t[j] = u > 0.f ? u : 0.f;
  }
  float o[16];
  for (int j = 0; j < nout; ++j) {
    float s = bb[j];
#pragma unroll
    for (int k = 0; k < 16; ++k) s += t[k] * w[k * nout + j];
    o[j] = s;
  }
  for (int j = 0; j < nout; ++j) p[j] = o[j];
}

__global__ void pos_mlp(const float* __restrict__ biases, const float* __restrict__ ppw,
                        const float* __restrict__ ppb,
                        const float* g1, const float* be1, const float* w1, const float* bb1,
                        const float* g2, const float* be2, const float* w2, const float* bb2,
                        const float* g3, const float* be3, const float* w3, const float* bb3,
                        float* __restrict__ p_out) {
  int i = blockIdx.x * blockDim.x + threadIdx.x;
  if (i >= 169) return;
  float p[16];
  float y0 = biases[2 * i], y1 = biases[2 * i + 1];
#pragma unroll
  for (int j = 0; j < 16; ++j) p[j] = y0 * ppw[j] + y1 * ppw[16 + j] + ppb[j];
  mlp_layer(p, g1, be1, w1, bb1, 16);
  mlp_layer(p, g2, be2, w2, bb2, 16);
  mlp_layer(p, g3, be3, w3, bb3, 8);
#pragma unroll
  for (int j = 0; j < 8; ++j) p_out[i * 8 + j] = p[j];
}

// rpbT[h][kt][qt], 8 x 64 x 64, pre-scaled by LOG2E, key-mask baked in.
__global__ void build_rpbT(const float* __restrict__ p, const int* __restrict__ rel_idx,
                           float* __restrict__ rpbT) {
  int tid = blockIdx.x * 256 + threadIdx.x;
  if (tid >= 8 * 64 * 64) return;
  int h = tid >> 12, rem = tid & 4095, kt = rem >> 6, qt = rem & 63;
  float v;
  if (kt >= NTOK) v = -1e30f;                      // padded key -> exp2 -> 0
  else if (qt >= NTOK) v = 0.f;                    // padded query row -> harmless
  else v = p[rel_idx[qt * NTOK + kt] * 8 + h] * LOG2E;
  rpbT[tid] = v;
}

// ---------------- fused per-window attention ----------------
// block = 256 threads (4 waves) = 1 window. Heads sequential (h-loop fully
// unrolled so per-head accumulators stay in REGISTERS - R2's scratch bug).
// wave w owns q-rows [16w,16w+16). LDS (47616 B -> 3 blocks/CU):
//   x_lds 64x256 bf16 XOR-swizzled (32768 B) - reused as attn-out for proj
//   sbuf  q 64x40 | k 64x40 (10240 B) ; P 64x72 overlays q+k
//   vT    32x72 bf16 (4608 B)
// MFMA 16x16x32 bf16 layouts (m89/m92-verified):
//   A-frag: row = lane&15, k = 8*(lane>>4)+j ; B-frag: col = lane&15, k contiguous
//   C/D:    col = lane&15, row = 4*(lane>>4)+reg
__launch_bounds__(256, 3)
__global__ void attn_fused(const float* __restrict__ x, const bf16* __restrict__ wT,
                           const float* __restrict__ qkv_b, const bf16* __restrict__ pjT,
                           const float* __restrict__ proj_b, const float* __restrict__ rpbT,
                           float* __restrict__ out) {
  __shared__ __align__(16) bf16 x_lds[64 * 256];   // swizzled: byte ^= (row&7)<<4
  __shared__ __align__(16) bf16 sbuf[2 * 64 * 40]; // q | k ; P overlays
  __shared__ __align__(16) bf16 vT[32 * 72];       // vT[d][token]

  const int b = blockIdx.x;
  const int tid = threadIdx.x;
  const int w = tid >> 6;
  const int lane = tid & 63;
  const int lg = lane >> 4;
  const int lr = lane & 15;
  const int rowbase = w * 16;
  const int myrow = rowbase + 4 * lg;

  char* const xbase = (char*)x_lds;

  // ---- phase 0: x -> bf16 LDS (swizzled), rows >= 49 zeroed ----
  const float* xb = x + (size_t)b * (NTOK * 256);
#pragma unroll
  for (int it = 0; it < 16; ++it) {
    int r = it * 4 + w;               // uniform per wave
    int c4 = lane;                    // f32x4 chunk index 0..63
    float4 v = make_float4(0.f, 0.f, 0.f, 0.f);
    if (r < NTOK) v = *(const float4*)(xb + r * 256 + 4 * c4);
    bf16x4 pk;
    pk[0] = (bf16)v.x; pk[1] = (bf16)v.y; pk[2] = (bf16)v.z; pk[3] = (bf16)v.w;
    *(bf16x4*)(xbase + r * 512 + ((8 * c4) ^ ((r & 7) << 4))) = pk;
  }
  __syncthreads();

  bf16* const q_lds = sbuf;            // 64 x 40
  bf16* const k_lds = sbuf + 2560;     // 64 x 40
  bf16* const P     = sbuf;            // 64 x 72, overlays q+k

  const f32x4 zero4 = {0.f, 0.f, 0.f, 0.f};
  bf16x4 o_pk[8][2];                   // per-head attn out, registers (h unrolled)

#pragma unroll
  for (int h = 0; h < 8; ++h) {
    // ---- GEMM1: rows [16w,16w+16) x 96 qkv cols of head h ----
    f32x4 acc[6];
    const bf16* wrow[6];
#pragma unroll
    for (int n = 0; n < 6; ++n) {
      const int colb = (n < 2) ? (h * 32 + n * 16)
                     : (n < 4) ? (256 + h * 32 + (n - 2) * 16)
                               : (512 + h * 32 + (n - 4) * 16);
      const float bz = qkv_b[colb + lr];           // bias folded into C-init
      acc[n][0] = bz; acc[n][1] = bz; acc[n][2] = bz; acc[n][3] = bz;
      wrow[n] = wT + (size_t)(colb + lr) * 256 + 8 * lg;
    }
#pragma unroll
    for (int kk = 0; kk < 8; ++kk) {
      bf16x8 afr = *(const bf16x8*)(xbase + (rowbase + lr) * 512 +
                                    ((64 * kk + 16 * lg) ^ ((lr & 7) << 4)));
#pragma unroll
      for (int n = 0; n < 6; ++n) {
        bf16x8 bfr = *(const bf16x8*)&wrow[n][kk * 32];
        acc[n] = __builtin_amdgcn_mfma_f32_16x16x32_bf16(afr, bfr, acc[n], 0, 0, 0);
      }
    }

    __syncthreads();  // (1) prev head's q/k/vT/P reads complete

    // ---- stash q (pre-scaled by SCALE*log2e), k, vT ----
#pragma unroll
    for (int n = 0; n < 2; ++n)
#pragma unroll
      for (int r2 = 0; r2 < 4; ++r2)
        q_lds[(myrow + r2) * 40 + n * 16 + lr] = (bf16)(acc[n][r2] * QS);
#pragma unroll
    for (int n = 2; n < 4; ++n)
#pragma unroll
      for (int r2 = 0; r2 < 4; ++r2)
        k_lds[(myrow + r2) * 40 + (n - 2) * 16 + lr] = (bf16)acc[n][r2];
#pragma unroll
    for (int n = 4; n < 6; ++n) {
      bf16x4 pk;
#pragma unroll
      for (int r2 = 0; r2 < 4; ++r2) pk[r2] = (bf16)acc[n][r2];
      *(bf16x4*)&vT[((n - 4) * 16 + lr) * 72 + myrow] = pk;
    }
    __syncthreads();  // (2) q/k/vT visible

    // ---- QK^T with rpb as the MFMA C-operand (log2-domain) ----
    const float* rpbh = rpbT + h * 4096;
    bf16x8 aq = *(const bf16x8*)&q_lds[(rowbase + lr) * 40 + 8 * lg];
    f32x4 s[4];
#pragma unroll
    for (int n = 0; n < 4; ++n) {
      bf16x8 bk = *(const bf16x8*)&k_lds[(n * 16 + lr) * 40 + 8 * lg];
      f32x4 rv = *(const f32x4*)&rpbh[(n * 16 + lr) * 64 + myrow];
      s[n] = __builtin_amdgcn_mfma_f32_16x16x32_bf16(aq, bk, rv, 0, 0, 0);
    }

    // ---- softmax (base-2) ----
    float inv_[4];
#pragma unroll
    for (int r2 = 0; r2 < 4; ++r2) {
      float mx = fmaxf(fmaxf(s[0][r2], s[1][r2]), fmaxf(s[2][r2], s[3][r2]));
#pragma unroll
      for (int off = 1; off <= 8; off <<= 1) mx = fmaxf(mx, __shfl_xor(mx, off, 64));
      float sum = 0.f;
#pragma unroll
      for (int n = 0; n < 4; ++n) {
        float e = exp2f(s[n][r2] - mx);
        s[n][r2] = e;
        sum += e;
      }
#pragma unroll
      for (int off = 1; off <= 8; off <<= 1) sum += __shfl_xor(sum, off, 64);
      inv_[r2] = 1.f / sum;
    }

    __syncthreads();  // (3) all waves' q/k reads done; safe to overlay P

    // ---- P -> LDS (own rows; consumed same-wave) ----
#pragma unroll
    for (int n = 0; n < 4; ++n)
#pragma unroll
      for (int r2 = 0; r2 < 4; ++r2)
        P[(myrow + r2) * 72 + n * 16 + lr] = (bf16)s[n][r2];

    // ---- PV: o(16x32) = P(16x64) @ v(64x32) ----
    f32x4 o[2];
    o[0] = zero4; o[1] = zero4;
#pragma unroll
    for (int ks = 0; ks < 2; ++ks) {
      bf16x8 ap = *(const bf16x8*)&P[(rowbase + lr) * 72 + ks * 32 + 8 * lg];
#pragma unroll
      for (int n2 = 0; n2 < 2; ++n2) {
        bf16x8 bv = *(const bf16x8*)&vT[(n2 * 16 + lr) * 72 + ks * 32 + 8 * lg];
        o[n2] = __builtin_amdgcn_mfma_f32_16x16x32_bf16(ap, bv, o[n2], 0, 0, 0);
      }
    }
#pragma unroll
    for (int n2 = 0; n2 < 2; ++n2)
#pragma unroll
      for (int r2 = 0; r2 < 4; ++r2)
        o_pk[h][n2][r2] = (bf16)(o[n2][r2] * inv_[r2]);
  }

  __syncthreads();  // x_lds dead; P/vT reads done

  // ---- assemble attn-out tile into x_lds (same swizzle) ----
#pragma unroll
  for (int h = 0; h < 8; ++h)
#pragma unroll
    for (int n2 = 0; n2 < 2; ++n2)
#pragma unroll
      for (int r2 = 0; r2 < 4; ++r2) {
        const int r = myrow + r2;
        *(bf16*)(xbase + r * 512 +
                 ((2 * (h * 32 + n2 * 16 + lr)) ^ ((r & 7) << 4))) = o_pk[h][n2][r2];
      }
  __syncthreads();

  // ---- proj: out = ao(64x256) @ proj_w + b; wave w owns 64 output cols ----
  f32x4 c2[4][4];
  const bf16* pjrow[4];
#pragma unroll
  for (int n = 0; n < 4; ++n) {
    const int col = w * 64 + n * 16 + lr;
    const float pb = proj_b[col];                  // bias folded into C-init
#pragma unroll
    for (int m = 0; m < 4; ++m) {
      c2[m][n][0] = pb; c2[m][n][1] = pb; c2[m][n][2] = pb; c2[m][n][3] = pb;
    }
    pjrow[n] = pjT + (size_t)col * 256 + 8 * lg;
  }
#pragma unroll
  for (int kk = 0; kk < 8; ++kk) {
    bf16x8 afr[4];
#pragma unroll
    for (int m = 0; m < 4; ++m)
      afr[m] = *(const bf16x8*)(xbase + (m * 16 + lr) * 512 +
                                ((64 * kk + 16 * lg) ^ ((lr & 7) << 4)));
#pragma unroll
    for (int n = 0; n < 4; ++n) {
      bf16x8 bfr = *(const bf16x8*)&pjrow[n][kk * 32];
#pragma unroll
      for (int m = 0; m < 4; ++m)
        c2[m][n] = __builtin_amdgcn_mfma_f32_16x16x32_bf16(afr[m], bfr, c2[m][n], 0, 0, 0);
    }
  }
  float* ob = out + (size_t)b * (NTOK * 256);
#pragma unroll
  for (int n = 0; n < 4; ++n) {
    const int col = w * 64 + n * 16 + lr;
#pragma unroll
    for (int m = 0; m < 4; ++m)
#pragma unroll
      for (int r2 = 0; r2 < 4; ++r2) {
        const int row = m * 16 + lg * 4 + r2;
        if (row < NTOK) ob[row * 256 + col] = c2[m][n][r2];
      }
  }
}

// ---------------- launcher ----------------
extern "C" void kernel_launch(void* const* d_in, const int* in_sizes, int n_in,
                              void* d_out, int out_size, void* d_ws, size_t ws_size,
                              hipStream_t stream) {
  (void)in_sizes; (void)n_in; (void)out_size; (void)ws_size;
  const float* x      = (const float*)d_in[0];
  const float* qkv_w  = (const float*)d_in[1];
  const float* qkv_b  = (const float*)d_in[2];
  const float* proj_w = (const float*)d_in[3];
  const float* proj_b = (const float*)d_in[4];
  const float* ppw    = (const float*)d_in[5];
  const float* ppb    = (const float*)d_in[6];
  const float* ln1_g  = (const float*)d_in[7];
  const float* ln1_b  = (const float*)d_in[8];
  const float* w1     = (const float*)d_in[9];
  const float* b1     = (const float*)d_in[10];
  const float* ln2_g  = (const float*)d_in[11];
  const float* ln2_b  = (const float*)d_in[12];
  const float* w2     = (const float*)d_in[13];
  const float* b2     = (const float*)d_in[14];
  const float* ln3_g  = (const float*)d_in[15];
  const float* ln3_b  = (const float*)d_in[16];
  const float* w3     = (const float*)d_in[17];
  const float* b3     = (const float*)d_in[18];
  const float* biases = (const float*)d_in[19];
  const int*   relidx = (const int*)d_in[20];

  char* ws = (char*)d_ws;
  bf16*  wT   = (bf16*)(ws + WS_WT);
  bf16*  pjT  = (bf16*)(ws + WS_PJT);
  float* p_ws = (float*)(ws + WS_P);
  float* rpbT = (float*)(ws + WS_RPBT);

  prep_weights<<<1024, 256, 0, stream>>>(qkv_w, proj_w, wT, pjT);
  pos_mlp<<<1, 256, 0, stream>>>(biases, ppw, ppb,
                                 ln1_g, ln1_b, w1, b1,
                                 ln2_g, ln2_b, w2, b2,
                                 ln3_g, ln3_b, w3, b3, p_ws);
  build_rpbT<<<128, 256, 0, stream>>>(p_ws, relidx, rpbT);
  attn_fused<<<4096, 256, 0, stream>>>(x, wT, qkv_b, pjT, proj_b, rpbT, (float*)d_out);
}

// Round 4
// 538.660 us; speedup vs baseline: 1.8979x; 1.6760x over previous
//
#include <hip/hip_runtime.h>
#include <cstddef>
#include <cstdint>

typedef __bf16 bf16;
typedef __bf16 bf16x8 __attribute__((ext_vector_type(8)));
typedef __bf16 bf16x4 __attribute__((ext_vector_type(4)));
typedef float  f32x4  __attribute__((ext_vector_type(4)));

#define NTOK 49
#define QK_SCALE 0.17677669529663687f   // 32^-0.5
#define LOG2E    1.4426950408889634f
#define QS       (QK_SCALE * LOG2E)     // folded into wT q-cols (prep) + q bias

// workspace byte offsets
#define WS_WT   0          // 768*256 bf16 = 393216 B
#define WS_PJT  393216     // 256*256 bf16 = 131072 B
#define WS_P    524288     // 169*8 f32 (padded to 8192)
#define WS_RPBT 532480     // 8*64*64 f32 = 131072 B (end: 663552)

// ---------------- prep: transpose + bf16-convert weights ----------------
// q-columns (n < 256) pre-scaled by QK_SCALE*LOG2E so softmax runs in exp2.
__global__ void prep_weights(const float* __restrict__ qkv_w, const float* __restrict__ proj_w,
                             bf16* __restrict__ wT, bf16* __restrict__ pjT) {
  int tid = blockIdx.x * 256 + threadIdx.x;
  if (tid < 768 * 256) {
    int n = tid >> 8, k = tid & 255;
    float v = qkv_w[k * 768 + n];
    if (n < 256) v *= QS;
    wT[tid] = (bf16)v;                          // wT[n][k]
  } else {
    int t = tid - 768 * 256;
    int n = t >> 8, k = t & 255;
    pjT[t] = (bf16)proj_w[k * 256 + n];         // pjT[n][k]
  }
}

// ---------------- prep: position-bias MLP (169 rows, tiny) ----------------
__device__ __forceinline__ void mlp_layer(float* p, const float* g, const float* be,
                                          const float* w, const float* bb, int nout) {
  float m = 0.f;
#pragma unroll
  for (int j = 0; j < 16; ++j) m += p[j];
  m *= (1.f / 16.f);
  float v = 0.f;
#pragma unroll
  for (int j = 0; j < 16; ++j) { float d = p[j] - m; v += d * d; }
  v *= (1.f / 16.f);
  float rs = rsqrtf(v + 1e-5f);
  float t[16];
#pragma unroll
  for (int j = 0; j < 16; ++j) {
    float u = (p[j] - m) * rs * g[j] + be[j];
    t[j] = u > 0.f ? u : 0.f;
  }
  float o[16];
  for (int j = 0; j < nout; ++j) {
    float s = bb[j];
#pragma unroll
    for (int k = 0; k < 16; ++k) s += t[k] * w[k * nout + j];
    o[j] = s;
  }
  for (int j = 0; j < nout; ++j) p[j] = o[j];
}

__global__ void pos_mlp(const float* __restrict__ biases, const float* __restrict__ ppw,
                        const float* __restrict__ ppb,
                        const float* g1, const float* be1, const float* w1, const float* bb1,
                        const float* g2, const float* be2, const float* w2, const float* bb2,
                        const float* g3, const float* be3, const float* w3, const float* bb3,
                        float* __restrict__ p_out) {
  int i = blockIdx.x * blockDim.x + threadIdx.x;
  if (i >= 169) return;
  float p[16];
  float y0 = biases[2 * i], y1 = biases[2 * i + 1];
#pragma unroll
  for (int j = 0; j < 16; ++j) p[j] = y0 * ppw[j] + y1 * ppw[16 + j] + ppb[j];
  mlp_layer(p, g1, be1, w1, bb1, 16);
  mlp_layer(p, g2, be2, w2, bb2, 16);
  mlp_layer(p, g3, be3, w3, bb3, 8);
#pragma unroll
  for (int j = 0; j < 8; ++j) p_out[i * 8 + j] = p[j];
}

// rpbT[h][kt][qt], 8 x 64 x 64, pre-scaled by LOG2E, key-mask baked in.
__global__ void build_rpbT(const float* __restrict__ p, const int* __restrict__ rel_idx,
                           float* __restrict__ rpbT) {
  int tid = blockIdx.x * 256 + threadIdx.x;
  if (tid >= 8 * 64 * 64) return;
  int h = tid >> 12, rem = tid & 4095, kt = rem >> 6, qt = rem & 63;
  float v;
  if (kt >= NTOK) v = -1e30f;                      // padded key -> exp2 -> 0
  else if (qt >= NTOK) v = 0.f;                    // padded query row -> harmless
  else v = p[rel_idx[qt * NTOK + kt] * 8 + h] * LOG2E;
  rpbT[tid] = v;
}

// ---------------- helpers ----------------
__device__ __forceinline__ uint2 pack4(f32x4 a) {
  union { bf16x4 v; uint2 u; } t;
  t.v[0] = (bf16)a[0]; t.v[1] = (bf16)a[1]; t.v[2] = (bf16)a[2]; t.v[3] = (bf16)a[3];
  return t.u;
}

// C-layout tile pair (pk0: rows 0-15, pk1: rows 16-31 of a 32-dim axis;
// each uint2 = bf16x4 of r2=0..3) -> A/B-frag (row=lane&15, k=8*(lane>>4)+i).
__device__ __forceinline__ bf16x8 xpose_frag(uint2 pk0, uint2 pk1, int lg, int lr) {
  const int sl0 = ((lg & 1) << 5) + lr;   // source lane group 2*(lg&1)
  const int sl1 = sl0 + 16;               // source lane group 2*(lg&1)+1
  const bool hi = lg >= 2;
  uint32_t a0 = (uint32_t)__shfl((int)pk0.x, sl0, 64);
  uint32_t b0 = (uint32_t)__shfl((int)pk1.x, sl0, 64);
  uint32_t a1 = (uint32_t)__shfl((int)pk0.y, sl0, 64);
  uint32_t b1 = (uint32_t)__shfl((int)pk1.y, sl0, 64);
  uint32_t a2 = (uint32_t)__shfl((int)pk0.x, sl1, 64);
  uint32_t b2 = (uint32_t)__shfl((int)pk1.x, sl1, 64);
  uint32_t a3 = (uint32_t)__shfl((int)pk0.y, sl1, 64);
  uint32_t b3 = (uint32_t)__shfl((int)pk1.y, sl1, 64);
  union { uint32_t u[4]; bf16x8 v; } r;
  r.u[0] = hi ? b0 : a0; r.u[1] = hi ? b1 : a1;
  r.u[2] = hi ? b2 : a2; r.u[3] = hi ? b3 : a3;
  return r.v;
}

// ---------------- fused per-window attention ----------------
// block = 256 threads (4 waves) = 1 window. Wave w owns heads {w, 4+w} fully
// (64 tokens x head). q,k,v stay in REGISTERS via xpose_frag (C->frag wave
// transpose); only P round-trips through a private 4KB LDS half-buffer.
// NO barriers inside the head loop (3 per block total).
// LDS: x_lds 32768 (swizzled, reused as attn-out) + Pw 4x4096 = 49152 B
//   -> 3 blocks/CU.
__launch_bounds__(256, 3)
__global__ void attn_fused(const float* __restrict__ x, const bf16* __restrict__ wT,
                           const float* __restrict__ qkv_b, const bf16* __restrict__ pjT,
                           const float* __restrict__ proj_b, const float* __restrict__ rpbT,
                           float* __restrict__ out) {
  __shared__ __align__(16) bf16 x_lds[64 * 256];   // byte ^= (row&7)<<4
  __shared__ __align__(16) bf16 Pw_all[4][2048];   // per-wave P [64][32] bf16, swizzled

  const int b = blockIdx.x;
  const int tid = threadIdx.x;
  const int w = tid >> 6;
  const int lane = tid & 63;
  const int lg = lane >> 4;
  const int lr = lane & 15;

  char* const xbase = (char*)x_lds;
  char* const Pb = (char*)Pw_all[w];

  // ---- stage x -> bf16 LDS (swizzled), rows >= 49 zeroed ----
  const float* xb = x + (size_t)b * (NTOK * 256);
#pragma unroll
  for (int it = 0; it < 16; ++it) {
    int r = it * 4 + w;
    float4 v = make_float4(0.f, 0.f, 0.f, 0.f);
    if (r < NTOK) v = *(const float4*)(xb + r * 256 + 4 * lane);
    bf16x4 pk;
    pk[0] = (bf16)v.x; pk[1] = (bf16)v.y; pk[2] = (bf16)v.z; pk[3] = (bf16)v.w;
    *(bf16x4*)(xbase + r * 512 + ((8 * lane) ^ ((r & 7) << 4))) = pk;
  }
  __syncthreads();

  const f32x4 zero4 = {0.f, 0.f, 0.f, 0.f};
  bf16x4 o_pk[2][4][2];   // [hi][mq][nv], static-indexed (hi loop unrolled)

#pragma unroll
  for (int hi = 0; hi < 2; ++hi) {
    const int h = hi * 4 + w;

    // ---- qT & kT GEMM: [64 dims(q),64 dims(k)] x [64 tokens], K=256 ----
    f32x4 aq_[2][4], ak_[2][4];
#pragma unroll
    for (int mt = 0; mt < 2; ++mt)
#pragma unroll
      for (int nt = 0; nt < 4; ++nt) { aq_[mt][nt] = zero4; ak_[mt][nt] = zero4; }

#pragma unroll
    for (int kk = 0; kk < 8; ++kk) {
      bf16x8 xf[4];
#pragma unroll
      for (int nt = 0; nt < 4; ++nt)
        xf[nt] = *(const bf16x8*)(xbase + (nt * 16 + lr) * 512 +
                                  ((64 * kk + 16 * lg) ^ ((lr & 7) << 4)));
#pragma unroll
      for (int mt = 0; mt < 2; ++mt) {
        bf16x8 wqf = *(const bf16x8*)&wT[(size_t)(h * 32 + mt * 16 + lr) * 256 + kk * 32 + 8 * lg];
        bf16x8 wkf = *(const bf16x8*)&wT[(size_t)(256 + h * 32 + mt * 16 + lr) * 256 + kk * 32 + 8 * lg];
#pragma unroll
        for (int nt = 0; nt < 4; ++nt) {
          aq_[mt][nt] = __builtin_amdgcn_mfma_f32_16x16x32_bf16(wqf, xf[nt], aq_[mt][nt], 0, 0, 0);
          ak_[mt][nt] = __builtin_amdgcn_mfma_f32_16x16x32_bf16(wkf, xf[nt], ak_[mt][nt], 0, 0, 0);
        }
      }
    }

    // ---- bias + pack to bf16 (C rows = dims: bias varies with r2) ----
    uint2 pkq[2][4], pkk[2][4];
#pragma unroll
    for (int mt = 0; mt < 2; ++mt) {
      f32x4 qb = *(const f32x4*)&qkv_b[h * 32 + mt * 16 + 4 * lg];
      f32x4 kb = *(const f32x4*)&qkv_b[256 + h * 32 + mt * 16 + 4 * lg];
#pragma unroll
      for (int nt = 0; nt < 4; ++nt) {
        f32x4 tq, tk;
#pragma unroll
        for (int r2 = 0; r2 < 4; ++r2) {
          tq[r2] = aq_[mt][nt][r2] + qb[r2] * QS;
          tk[r2] = ak_[mt][nt][r2] + kb[r2];
        }
        pkq[mt][nt] = pack4(tq);
        pkk[mt][nt] = pack4(tk);
      }
    }

    // ---- register transpose -> QK fragments ----
    bf16x8 aqf[4], bkf[4];
#pragma unroll
    for (int t = 0; t < 4; ++t) {
      aqf[t] = xpose_frag(pkq[0][t], pkq[1][t], lg, lr);
      bkf[t] = xpose_frag(pkk[0][t], pkk[1][t], lg, lr);
    }

    // ---- QK^T with rpb as C-init (log2 domain) ----
    const float* rpbh = rpbT + h * 4096;
    f32x4 S[4][4];
#pragma unroll
    for (int mq = 0; mq < 4; ++mq)
#pragma unroll
      for (int nk = 0; nk < 4; ++nk) {
        f32x4 rv = *(const f32x4*)&rpbh[(nk * 16 + lr) * 64 + mq * 16 + 4 * lg];
        S[mq][nk] = __builtin_amdgcn_mfma_f32_16x16x32_bf16(aqf[mq], bkf[nk], rv, 0, 0, 0);
      }

    // ---- softmax (base-2), rows = (mq, 4*lg+r2), cols across nk-regs + lr ----
    f32x4 inv4[4];
#pragma unroll
    for (int mq = 0; mq < 4; ++mq)
#pragma unroll
      for (int r2 = 0; r2 < 4; ++r2) {
        float mx = fmaxf(fmaxf(S[mq][0][r2], S[mq][1][r2]),
                         fmaxf(S[mq][2][r2], S[mq][3][r2]));
#pragma unroll
        for (int off = 1; off <= 8; off <<= 1) mx = fmaxf(mx, __shfl_xor(mx, off, 64));
        float sum = 0.f;
#pragma unroll
        for (int nk = 0; nk < 4; ++nk) {
          float e = exp2f(S[mq][nk][r2] - mx);
          S[mq][nk][r2] = e;
          sum += e;
        }
#pragma unroll
        for (int off = 1; off <= 8; off <<= 1) sum += __shfl_xor(sum, off, 64);
        inv4[mq][r2] = 1.f / sum;
      }

    // ---- P half 0 (keys 0..31) -> private LDS (swizzled) ----
#pragma unroll
    for (int mq = 0; mq < 4; ++mq)
#pragma unroll
      for (int kl = 0; kl < 2; ++kl)
#pragma unroll
        for (int r2 = 0; r2 < 4; ++r2) {
          const int row = mq * 16 + 4 * lg + r2;
          *(bf16*)(Pb + ((row * 64 + kl * 32 + 2 * lr) ^ ((row & 7) << 4))) =
              (bf16)S[mq][kl][r2];
        }

    // ---- v GEMM (normal orientation): [64 tokens] x [32 vdims], K=256 ----
    f32x4 av_[4][2];
#pragma unroll
    for (int m = 0; m < 4; ++m)
#pragma unroll
      for (int nv = 0; nv < 2; ++nv) av_[m][nv] = zero4;
#pragma unroll
    for (int kk = 0; kk < 8; ++kk) {
      bf16x8 xf[4];
#pragma unroll
      for (int m = 0; m < 4; ++m)
        xf[m] = *(const bf16x8*)(xbase + (m * 16 + lr) * 512 +
                                 ((64 * kk + 16 * lg) ^ ((lr & 7) << 4)));
#pragma unroll
      for (int nv = 0; nv < 2; ++nv) {
        bf16x8 wvf = *(const bf16x8*)&wT[(size_t)(512 + h * 32 + nv * 16 + lr) * 256 + kk * 32 + 8 * lg];
#pragma unroll
        for (int m = 0; m < 4; ++m)
          av_[m][nv] = __builtin_amdgcn_mfma_f32_16x16x32_bf16(xf[m], wvf, av_[m][nv], 0, 0, 0);
      }
    }
    // v bias (C cols = vdims: bias uniform over r2, varies with lr)
    uint2 pkv[4][2];
#pragma unroll
    for (int nv = 0; nv < 2; ++nv) {
      const float vb = qkv_b[512 + h * 32 + nv * 16 + lr];
#pragma unroll
      for (int m = 0; m < 4; ++m) {
        f32x4 tv;
#pragma unroll
        for (int r2 = 0; r2 < 4; ++r2) tv[r2] = av_[m][nv][r2] + vb;
        pkv[m][nv] = pack4(tv);
      }
    }

    // ---- PV ks=0 (keys 0..31) ----
    f32x4 o[4][2];
#pragma unroll
    for (int mq = 0; mq < 4; ++mq)
#pragma unroll
      for (int nv = 0; nv < 2; ++nv) o[mq][nv] = zero4;

    bf16x8 vf0[2], vf1[2];
#pragma unroll
    for (int nv = 0; nv < 2; ++nv) {
      vf0[nv] = xpose_frag(pkv[0][nv], pkv[1][nv], lg, lr);   // tokens 0..31
      vf1[nv] = xpose_frag(pkv[2][nv], pkv[3][nv], lg, lr);   // tokens 32..63
    }
#pragma unroll
    for (int mq = 0; mq < 4; ++mq) {
      bf16x8 pa = *(const bf16x8*)(Pb + (((mq * 16 + lr) * 64 + 16 * lg) ^ ((lr & 7) << 4)));
#pragma unroll
      for (int nv = 0; nv < 2; ++nv)
        o[mq][nv] = __builtin_amdgcn_mfma_f32_16x16x32_bf16(pa, vf0[nv], o[mq][nv], 0, 0, 0);
    }

    // ---- P half 1 (keys 32..63) -> same buffer; PV ks=1 ----
#pragma unroll
    for (int mq = 0; mq < 4; ++mq)
#pragma unroll
      for (int kl = 0; kl < 2; ++kl)
#pragma unroll
        for (int r2 = 0; r2 < 4; ++r2) {
          const int row = mq * 16 + 4 * lg + r2;
          *(bf16*)(Pb + ((row * 64 + kl * 32 + 2 * lr) ^ ((row & 7) << 4))) =
              (bf16)S[mq][2 + kl][r2];
        }
#pragma unroll
    for (int mq = 0; mq < 4; ++mq) {
      bf16x8 pa = *(const bf16x8*)(Pb + (((mq * 16 + lr) * 64 + 16 * lg) ^ ((lr & 7) << 4)));
#pragma unroll
      for (int nv = 0; nv < 2; ++nv)
        o[mq][nv] = __builtin_amdgcn_mfma_f32_16x16x32_bf16(pa, vf1[nv], o[mq][nv], 0, 0, 0);
    }

    // ---- normalize + hold packed ----
#pragma unroll
    for (int mq = 0; mq < 4; ++mq)
#pragma unroll
      for (int nv = 0; nv < 2; ++nv) {
        bf16x4 pk;
#pragma unroll
        for (int r2 = 0; r2 < 4; ++r2) pk[r2] = (bf16)(o[mq][nv][r2] * inv4[mq][r2]);
        o_pk[hi][mq][nv] = pk;
      }
  }

  __syncthreads();  // all x_lds reads done

  // ---- assemble attn-out tile into x_lds (same swizzle) ----
#pragma unroll
  for (int hi = 0; hi < 2; ++hi) {
    const int h = hi * 4 + w;
#pragma unroll
    for (int mq = 0; mq < 4; ++mq)
#pragma unroll
      for (int nv = 0; nv < 2; ++nv)
#pragma unroll
        for (int r2 = 0; r2 < 4; ++r2) {
          const int r = mq * 16 + 4 * lg + r2;
          *(bf16*)(xbase + r * 512 +
                   ((2 * (h * 32 + nv * 16 + lr)) ^ ((r & 7) << 4))) = o_pk[hi][mq][nv][r2];
        }
  }
  __syncthreads();

  // ---- proj: out = ao(64x256) @ proj_w + b; wave w owns 64 output cols ----
  f32x4 c2[4][4];
  const bf16* pjrow[4];
#pragma unroll
  for (int n = 0; n < 4; ++n) {
    const int col = w * 64 + n * 16 + lr;
    const float pb = proj_b[col];
#pragma unroll
    for (int m = 0; m < 4; ++m) {
      c2[m][n][0] = pb; c2[m][n][1] = pb; c2[m][n][2] = pb; c2[m][n][3] = pb;
    }
    pjrow[n] = pjT + (size_t)col * 256 + 8 * lg;
  }
#pragma unroll
  for (int kk = 0; kk < 8; ++kk) {
    bf16x8 afr[4];
#pragma unroll
    for (int m = 0; m < 4; ++m)
      afr[m] = *(const bf16x8*)(xbase + (m * 16 + lr) * 512 +
                                ((64 * kk + 16 * lg) ^ ((lr & 7) << 4)));
#pragma unroll
    for (int n = 0; n < 4; ++n) {
      bf16x8 bfr = *(const bf16x8*)&pjrow[n][kk * 32];
#pragma unroll
      for (int m = 0; m < 4; ++m)
        c2[m][n] = __builtin_amdgcn_mfma_f32_16x16x32_bf16(afr[m], bfr, c2[m][n], 0, 0, 0);
    }
  }
  float* ob = out + (size_t)b * (NTOK * 256);
#pragma unroll
  for (int n = 0; n < 4; ++n) {
    const int col = w * 64 + n * 16 + lr;
#pragma unroll
    for (int m = 0; m < 4; ++m)
#pragma unroll
      for (int r2 = 0; r2 < 4; ++r2) {
        const int row = m * 16 + lg * 4 + r2;
        if (row < NTOK) ob[row * 256 + col] = c2[m][n][r2];
      }
  }
}

// ---------------- launcher ----------------
extern "C" void kernel_launch(void* const* d_in, const int* in_sizes, int n_in,
                              void* d_out, int out_size, void* d_ws, size_t ws_size,
                              hipStream_t stream) {
  (void)in_sizes; (void)n_in; (void)out_size; (void)ws_size;
  const float* x      = (const float*)d_in[0];
  const float* qkv_w  = (const float*)d_in[1];
  const float* qkv_b  = (const float*)d_in[2];
  const float* proj_w = (const float*)d_in[3];
  const float* proj_b = (const float*)d_in[4];
  const float* ppw    = (const float*)d_in[5];
  const float* ppb    = (const float*)d_in[6];
  const float* ln1_g  = (const float*)d_in[7];
  const float* ln1_b  = (const float*)d_in[8];
  const float* w1     = (const float*)d_in[9];
  const float* b1     = (const float*)d_in[10];
  const float* ln2_g  = (const float*)d_in[11];
  const float* ln2_b  = (const float*)d_in[12];
  const float* w2     = (const float*)d_in[13];
  const float* b2     = (const float*)d_in[14];
  const float* ln3_g  = (const float*)d_in[15];
  const float* ln3_b  = (const float*)d_in[16];
  const float* w3     = (const float*)d_in[17];
  const float* b3     = (const float*)d_in[18];
  const float* biases = (const float*)d_in[19];
  const int*   relidx = (const int*)d_in[20];

  char* ws = (char*)d_ws;
  bf16*  wT   = (bf16*)(ws + WS_WT);
  bf16*  pjT  = (bf16*)(ws + WS_PJT);
  float* p_ws = (float*)(ws + WS_P);
  float* rpbT = (float*)(ws + WS_RPBT);

  prep_weights<<<1024, 256, 0, stream>>>(qkv_w, proj_w, wT, pjT);
  pos_mlp<<<1, 256, 0, stream>>>(biases, ppw, ppb,
                                 ln1_g, ln1_b, w1, b1,
                                 ln2_g, ln2_b, w2, b2,
                                 ln3_g, ln3_b, w3, b3, p_ws);
  build_rpbT<<<128, 256, 0, stream>>>(p_ws, relidx, rpbT);
  attn_fused<<<4096, 256, 0, stream>>>(x, wT, qkv_b, pjT, proj_b, rpbT, (float*)d_out);
}